// Round 8
// baseline (565.356 us; speedup 1.0000x reference)
//
#include <hip/hip_runtime.h>
#include <math.h>

// Problem constants (fixed by the reference)
#define B_N  16384
#define T_N  3
#define D_N  512
#define G_N  4
#define NE_N 4
#define H_N  512
#define E_N  256
#define GH_N 256
#define K16  16      // G*NE experts
#define TH_N 128
#define TO_N 64

typedef __attribute__((ext_vector_type(8))) short short8;
typedef __attribute__((ext_vector_type(4))) float floatx4;

__device__ __forceinline__ unsigned short f2bf(float f) {
    union { float f; unsigned u; } v; v.f = f;
    unsigned r = (v.u + 0x7fffu + ((v.u >> 16) & 1u)) >> 16;
    return (unsigned short)r;
}
__device__ __forceinline__ float bf2f(unsigned short h) {
    union { unsigned u; float f; } v; v.u = ((unsigned)h) << 16;
    return v.f;
}
__device__ __forceinline__ unsigned pack2(float lo, float hi) {
    return ((unsigned)f2bf(hi) << 16) | (unsigned)f2bf(lo);
}

typedef const __attribute__((address_space(1))) void gvoid_t;
typedef __attribute__((address_space(3))) void lvoid_t;

#if __has_builtin(__builtin_amdgcn_global_load_lds)
#define HAVE_GLL 1
__device__ __forceinline__ void load_lds16(const void* g, void* l) {
    __builtin_amdgcn_global_load_lds((gvoid_t*)g, (lvoid_t*)l, 16, 0, 0);
}
#else
#define HAVE_GLL 0
#endif

// ---------------------------------------------------------------------------
// Input cast: x -> bf16 [BC][G*D]; gin = x[:,1+t]+x[:,0] -> bf16 [BC][T*D]
// (standalone version, used only when the batch is chunked: n_o > 1)
// ---------------------------------------------------------------------------
__global__ __launch_bounds__(256) void convert_inputs(
    const float* __restrict__ x, unsigned short* __restrict__ xb,
    unsigned short* __restrict__ ginb)
{
    const long b = blockIdx.x;
    const int tid = threadIdx.x;           // 256 threads, 2 floats each per g
    const float* xr = x + b * (G_N * D_N);
    unsigned short* xo = xb + b * (G_N * D_N);
    unsigned short* go = ginb + b * (T_N * D_N);
    float2 v0 = *(const float2*)&xr[tid * 2];
    *(unsigned*)&xo[tid * 2] = pack2(v0.x, v0.y);
    #pragma unroll
    for (int g = 1; g < G_N; ++g) {
        float2 v = *(const float2*)&xr[g * D_N + tid * 2];
        *(unsigned*)&xo[g * D_N + tid * 2] = pack2(v.x, v.y);
        *(unsigned*)&go[(g - 1) * D_N + tid * 2] = pack2(v.x + v0.x, v.y + v0.y);
    }
}

// ---------------------------------------------------------------------------
// prep_kernel: ALL weight transposes (5 matrices, 6648 tiles) + input convert
// (nconv rows) in ONE launch.  1-D grid, segment decoded from blockIdx.x.
// ---------------------------------------------------------------------------
__global__ __launch_bounds__(256) void prep_kernel(
    const float* __restrict__ eW1, const float* __restrict__ eW2,
    const float* __restrict__ gW1, const float* __restrict__ tW1,
    const float* __restrict__ tW2,
    unsigned short* __restrict__ W1t, unsigned short* __restrict__ W2t,
    unsigned short* __restrict__ G1t, unsigned short* __restrict__ TW1t,
    unsigned short* __restrict__ TW2t,
    const float* __restrict__ x, unsigned short* __restrict__ xb,
    unsigned short* __restrict__ ginb)
{
    const int bid = blockIdx.x;
    if (bid < 6648) {
        const float* in; unsigned short* out; int K, N, nx, local;
        if (bid < 4096)      { in = eW1; out = W1t;  K = 512; N = 512; nx = 16; local = bid; }
        else if (bid < 6144) { in = eW2; out = W2t;  K = 512; N = 256; nx = 8;  local = bid - 4096; }
        else if (bid < 6528) { in = gW1; out = G1t;  K = 512; N = 256; nx = 8;  local = bid - 6144; }
        else if (bid < 6624) { in = tW1; out = TW1t; K = 256; N = 128; nx = 4;  local = bid - 6528; }
        else                 { in = tW2; out = TW2t; K = 128; N = 64;  nx = 2;  local = bid - 6624; }
        const int ny = K / 32;
        const int xt = local % nx;
        const int yt = (local / nx) % ny;
        const int z  = local / (nx * ny);
        __shared__ float tile[32][33];
        const int tx = threadIdx.x & 31, ty = threadIdx.x >> 5;   // (32,8)
        const long zo = (long)z * K * N;
        const int n0 = xt * 32, k0 = yt * 32;
        #pragma unroll
        for (int i = 0; i < 4; ++i)
            tile[ty + 8 * i][tx] = in[zo + (long)(k0 + ty + 8 * i) * N + n0 + tx];
        __syncthreads();
        #pragma unroll
        for (int i = 0; i < 4; ++i)
            out[zo + (long)(n0 + ty + 8 * i) * K + k0 + tx] = f2bf(tile[tx][ty + 8 * i]);
    } else {
        const long b = bid - 6648;
        const int tid = threadIdx.x;
        const float* xr = x + b * (G_N * D_N);
        unsigned short* xo = xb + b * (G_N * D_N);
        unsigned short* go = ginb + b * (T_N * D_N);
        float2 v0 = *(const float2*)&xr[tid * 2];
        *(unsigned*)&xo[tid * 2] = pack2(v0.x, v0.y);
        #pragma unroll
        for (int g = 1; g < G_N; ++g) {
            float2 v = *(const float2*)&xr[g * D_N + tid * 2];
            *(unsigned*)&xo[g * D_N + tid * 2] = pack2(v.x, v.y);
            *(unsigned*)&go[(g - 1) * D_N + tid * 2] = pack2(v.x + v0.x, v.y + v0.y);
        }
    }
}

// ---------------------------------------------------------------------------
// moe_fused: gate blocks (bid < 3*panels) + expert blocks (rest) in ONE
// launch — gate is data-independent of expert, and expert is issue-bound
// (MfmaUtil 33%), so gate hides under it.
//
// Gate branch (per block: 128 rows x task t), LDS 59.6 KB:
//   two 128-col halves: gh_half = relu(gin @ G1[:,half]) -> ghs[128][136]
//   (verified h1s pattern), then PARTIAL gate2 accumulate (exact: lg sums
//   linearly over k-halves).  Softmax at the end.  w2s[16][264] resident.
// Expert branch: verbatim harness-verified v1 (277us).  LDS 67.6 KB.
// Static LDS = 67584 B -> 2 blocks/CU for every block (unchanged).
// Gate blocks FIRST; 3*panels % 8 == 0 at full batch so the expert XCD
// decode (ebid&7 -> XCD) is unchanged.  Do NOT raise occupancy arg
// (round-4: (256,3) spilled the expert accumulators, 276->713us).
// ---------------------------------------------------------------------------
__global__ __launch_bounds__(256, 2) void moe_fused(
    const unsigned short* __restrict__ xb,      // [BC][2048] bf16
    const unsigned short* __restrict__ W1t,     // [16][512][512] bf16 (N-major)
    const float* __restrict__ eb1,              // [16][512]
    const unsigned short* __restrict__ W2t,     // [16][256][512] bf16 (N-major)
    const float* __restrict__ eb2,              // [16][256]
    unsigned short* __restrict__ embb,          // [BC][16*256] bf16
    const unsigned short* __restrict__ ginb,    // [BC][1536] bf16
    const unsigned short* __restrict__ G1t,     // [3][256][512] bf16 (N-major)
    const float* __restrict__ gb1,              // [3][256]
    const float* __restrict__ gW2,              // [3][256][16] fp32
    const float* __restrict__ gb2,              // [3][16]
    float* __restrict__ gw,                     // [BC][3][16] fp32
    int panels)
{
    __shared__ __align__(16) unsigned short sm[33792];   // 67584 B
    const int tid = threadIdx.x;
    const int bid = blockIdx.x;
    const int nGate = 3 * panels;

    const int lane16 = tid & 15;
    const int quad = (tid & 63) >> 4;
    const int wave = tid >> 6;
    const int srow = tid >> 2;
    const int scolsw = (((tid & 3) ^ ((tid >> 3) & 3)) * 8);
    const int cw8 = ((quad ^ ((lane16 >> 1) & 3)) * 8);
    const int wm = (wave >> 1) * 64;
    const int wn = (wave & 1) * 64;

    if (bid < nGate) {
        // ================= gate branch =================
        unsigned short* As  = sm;            // [128][32]  A staging   (8 KB w/ Bs)
        unsigned short* Bs  = sm + 4096;     // [128][32]  W1 staging
        unsigned short* w2s = sm + 8192;     // [16][264]  W2^T (resident)
        unsigned short* ghs = sm + 12416;    // [128][136] gh half-tile

        const int t = bid / panels;
        const long b0 = (long)(bid % panels) * 128;
        const unsigned short* Ab = ginb + b0 * 1536 + (long)t * 512;

        // stage W2^T once: w2s[n][k] = gW2[t][k][n]  (coalesced 64B/thread)
        {
            const float* W2p = gW2 + (long)t * (GH_N * K16) + (long)tid * K16;
            float4 w0 = *(const float4*)(W2p);
            float4 w1 = *(const float4*)(W2p + 4);
            float4 w2 = *(const float4*)(W2p + 8);
            float4 w3 = *(const float4*)(W2p + 12);
            w2s[ 0 * 264 + tid] = f2bf(w0.x); w2s[ 1 * 264 + tid] = f2bf(w0.y);
            w2s[ 2 * 264 + tid] = f2bf(w0.z); w2s[ 3 * 264 + tid] = f2bf(w0.w);
            w2s[ 4 * 264 + tid] = f2bf(w1.x); w2s[ 5 * 264 + tid] = f2bf(w1.y);
            w2s[ 6 * 264 + tid] = f2bf(w1.z); w2s[ 7 * 264 + tid] = f2bf(w1.w);
            w2s[ 8 * 264 + tid] = f2bf(w2.x); w2s[ 9 * 264 + tid] = f2bf(w2.y);
            w2s[10 * 264 + tid] = f2bf(w2.z); w2s[11 * 264 + tid] = f2bf(w2.w);
            w2s[12 * 264 + tid] = f2bf(w3.x); w2s[13 * 264 + tid] = f2bf(w3.y);
            w2s[14 * 264 + tid] = f2bf(w3.z); w2s[15 * 264 + tid] = f2bf(w3.w);
        }

        floatx4 ag[2] = {};                  // gate2 accumulator (both halves)
        #pragma unroll
        for (int ncc = 0; ncc < 2; ++ncc) {
            const unsigned short* Bb = G1t + (long)t * 131072 + (long)(ncc * 128) * 512;
            floatx4 acc[4][4] = {};
            for (int k0 = 0; k0 < 512; k0 += 32) {
#if HAVE_GLL
                load_lds16(Ab + (long)srow * 1536 + k0 + scolsw, &As[tid * 8]);
                load_lds16(Ab + (long)(srow + 64) * 1536 + k0 + scolsw, &As[2048 + tid * 8]);
                load_lds16(Bb + (long)srow * 512 + k0 + scolsw, &Bs[tid * 8]);
                load_lds16(Bb + (long)(srow + 64) * 512 + k0 + scolsw, &Bs[2048 + tid * 8]);
#else
                *(uint4*)&As[tid * 8] = *(const uint4*)(Ab + (long)srow * 1536 + k0 + scolsw);
                *(uint4*)&As[2048 + tid * 8] = *(const uint4*)(Ab + (long)(srow + 64) * 1536 + k0 + scolsw);
                *(uint4*)&Bs[tid * 8] = *(const uint4*)(Bb + (long)srow * 512 + k0 + scolsw);
                *(uint4*)&Bs[2048 + tid * 8] = *(const uint4*)(Bb + (long)(srow + 64) * 512 + k0 + scolsw);
#endif
                __syncthreads();
                short8 a[4], b[4];
                #pragma unroll
                for (int mi = 0; mi < 4; ++mi)
                    a[mi] = *(const short8*)&As[(wm + mi * 16 + lane16) * 32 + cw8];
                #pragma unroll
                for (int ni = 0; ni < 4; ++ni)
                    b[ni] = *(const short8*)&Bs[(wn + ni * 16 + lane16) * 32 + cw8];
                #pragma unroll
                for (int mi = 0; mi < 4; ++mi)
                    #pragma unroll
                    for (int ni = 0; ni < 4; ++ni)
                        acc[mi][ni] = __builtin_amdgcn_mfma_f32_16x16x32_bf16(
                            a[mi], b[ni], acc[mi][ni], 0, 0, 0);
                __syncthreads();
            }
            // gh-half epilogue -> ghs[128][136] (verified h1s pattern)
            #pragma unroll
            for (int mi = 0; mi < 4; ++mi) {
                #pragma unroll
                for (int ni = 0; ni < 4; ++ni) {
                    const int col = wn + ni * 16 + lane16;
                    const float bv = gb1[t * GH_N + ncc * 128 + col];
                    #pragma unroll
                    for (int r = 0; r < 4; ++r) {
                        const int row = wm + mi * 16 + quad * 4 + r;
                        ghs[row * 136 + col] = f2bf(fmaxf(acc[mi][ni][r] + bv, 0.0f));
                    }
                }
            }
            __syncthreads();
            // partial gate2: ag += gh_half @ w2s[:, half]^T
            #pragma unroll
            for (int kk = 0; kk < 4; ++kk) {
                short8 bfr = *(const short8*)&w2s[lane16 * 264 + ncc * 128 + kk * 32 + quad * 8];
                #pragma unroll
                for (int mi = 0; mi < 2; ++mi) {
                    const int row = wave * 32 + mi * 16 + lane16;
                    short8 afr = *(const short8*)&ghs[row * 136 + kk * 32 + quad * 8];
                    ag[mi] = __builtin_amdgcn_mfma_f32_16x16x32_bf16(afr, bfr, ag[mi], 0, 0, 0);
                }
            }
        }

        // softmax over the 16 n-lanes, then store gw
        const float bb2 = gb2[t * K16 + lane16];
        #pragma unroll
        for (int mi = 0; mi < 2; ++mi) {
            float v[4];
            #pragma unroll
            for (int r = 0; r < 4; ++r) v[r] = ag[mi][r] + bb2;
            #pragma unroll
            for (int r = 0; r < 4; ++r) {
                float mv = v[r];
                #pragma unroll
                for (int d = 1; d < 16; d <<= 1) mv = fmaxf(mv, __shfl_xor(mv, d));
                float e = expf(v[r] - mv);
                float s = e;
                #pragma unroll
                for (int d = 1; d < 16; d <<= 1) s += __shfl_xor(s, d);
                const int row = wave * 32 + mi * 16 + quad * 4 + r;
                gw[(b0 + row) * (T_N * K16) + (long)t * K16 + lane16] = e / s;
            }
        }
        return;
    }

    // ================= expert branch (verbatim v1) =================
    unsigned short* As  = sm;            // [2][4096]  (stage-1 A / stage-2 W2 tile)
    unsigned short* Bs  = sm + 8192;     // [2][4096]  (stage-1 W1 tile)
    unsigned short* h1s = sm + 16384;    // [128][136] (h1 chunk, padded)

    const unsigned ebid = bid - nGate;
    const int e = ((ebid & 7) << 1) | ((ebid >> 3) & 1);
    const long m0 = (long)(ebid >> 4) * 128;
    const int g = e >> 2;

    const unsigned short* Ab  = xb + m0 * 2048 + g * 512;    // row stride 2048
    const unsigned short* W1b = W1t + (long)e * (512 * 512);
    const unsigned short* W2b = W2t + (long)e * (256 * 512);

    const int wn2 = (wave & 1) * 128;    // stage-2 col-block

    floatx4 acc2[4][8] = {};             // emb accumulator (persists all chunks)

    for (int nc = 0; nc < 4; ++nc) {
        const unsigned short* Bb = W1b + ((long)nc << 16);   // nc*128*512
        floatx4 acc[4][4] = {};
        // ---- stage 1: h1c = relu(x @ W1[:, nc*128 : +128]) --------------
        for (int k0 = 0; k0 < 512; k0 += 64) {
            #pragma unroll
            for (int h = 0; h < 2; ++h) {
                const int kh = k0 + h * 32;
#if HAVE_GLL
                load_lds16(Ab + (long)srow * 2048 + kh + scolsw, &As[h * 4096 + tid * 8]);
                load_lds16(Ab + (long)(srow + 64) * 2048 + kh + scolsw, &As[h * 4096 + 2048 + tid * 8]);
                load_lds16(Bb + (long)srow * 512 + kh + scolsw, &Bs[h * 4096 + tid * 8]);
                load_lds16(Bb + (long)(srow + 64) * 512 + kh + scolsw, &Bs[h * 4096 + 2048 + tid * 8]);
#else
                *(uint4*)&As[h * 4096 + tid * 8] = *(const uint4*)(Ab + (long)srow * 2048 + kh + scolsw);
                *(uint4*)&As[h * 4096 + 2048 + tid * 8] = *(const uint4*)(Ab + (long)(srow + 64) * 2048 + kh + scolsw);
                *(uint4*)&Bs[h * 4096 + tid * 8] = *(const uint4*)(Bb + (long)srow * 512 + kh + scolsw);
                *(uint4*)&Bs[h * 4096 + 2048 + tid * 8] = *(const uint4*)(Bb + (long)(srow + 64) * 512 + kh + scolsw);
#endif
            }
            __syncthreads();
            #pragma unroll
            for (int h = 0; h < 2; ++h) {
                short8 b[4];
                #pragma unroll
                for (int ni = 0; ni < 4; ++ni)
                    b[ni] = *(const short8*)&Bs[h * 4096 + (wn + ni * 16 + lane16) * 32 + cw8];
                #pragma unroll
                for (int mi = 0; mi < 4; ++mi) {
                    short8 a = *(const short8*)&As[h * 4096 + (wm + mi * 16 + lane16) * 32 + cw8];
                    #pragma unroll
                    for (int ni = 0; ni < 4; ++ni)
                        acc[mi][ni] = __builtin_amdgcn_mfma_f32_16x16x32_bf16(
                            a, b[ni], acc[mi][ni], 0, 0, 0);
                }
            }
            __syncthreads();
        }
        // ---- h1 epilogue -> LDS (bf16, stride 136: 2-way banks only) ----
        #pragma unroll
        for (int mi = 0; mi < 4; ++mi) {
            #pragma unroll
            for (int ni = 0; ni < 4; ++ni) {
                const int col = wn + ni * 16 + lane16;
                const float bv = eb1[e * 512 + nc * 128 + col];
                #pragma unroll
                for (int r = 0; r < 4; ++r) {
                    const int row = wm + mi * 16 + quad * 4 + r;
                    h1s[row * 136 + col] = f2bf(fmaxf(acc[mi][ni][r] + bv, 0.0f));
                }
            }
        }
        __syncthreads();
        // ---- stage 2: acc2 += h1c @ W2[nc*128:+128, :] -------------------
        #pragma unroll
        for (int ks = 0; ks < 128; ks += 32) {
            #pragma unroll
            for (int i = 0; i < 4; ++i) {
#if HAVE_GLL
                load_lds16(W2b + (long)(srow + 64 * i) * 512 + nc * 128 + ks + scolsw,
                           &As[i * 2048 + tid * 8]);
#else
                *(uint4*)&As[i * 2048 + tid * 8] =
                    *(const uint4*)(W2b + (long)(srow + 64 * i) * 512 + nc * 128 + ks + scolsw);
#endif
            }
            __syncthreads();
            #pragma unroll
            for (int nh = 0; nh < 2; ++nh) {
                short8 b2[4];
                #pragma unroll
                for (int nj = 0; nj < 4; ++nj)
                    b2[nj] = *(const short8*)&As[(wn2 + nh * 64 + nj * 16 + lane16) * 32 + cw8];
                #pragma unroll
                for (int mi = 0; mi < 4; ++mi) {
                    short8 a2 = *(const short8*)&h1s[(wm + mi * 16 + lane16) * 136 + ks + quad * 8];
                    #pragma unroll
                    for (int nj = 0; nj < 4; ++nj)
                        acc2[mi][nh * 4 + nj] = __builtin_amdgcn_mfma_f32_16x16x32_bf16(
                            a2, b2[nj], acc2[mi][nh * 4 + nj], 0, 0, 0);
                }
            }
            __syncthreads();
        }
    }

    // ---- final epilogue: emb -> bf16 embb -------------------------------
    unsigned short* Cb = embb + m0 * 4096 + (long)e * 256;
    #pragma unroll
    for (int mi = 0; mi < 4; ++mi) {
        #pragma unroll
        for (int j = 0; j < 8; ++j) {
            const int col = wn2 + (j >> 2) * 64 + (j & 3) * 16 + lane16;
            const float bv = eb2[e * 256 + col];
            #pragma unroll
            for (int r = 0; r < 4; ++r) {
                const int row = wm + mi * 16 + quad * 4 + r;
                Cb[(long)row * 4096 + col] = f2bf(acc2[mi][j][r] + bv);
            }
        }
    }
}

// ---------------------------------------------------------------------------
// agg_tower: per block = (128-row panel, task t).  Fuses:
//   phase 1: aggA[128][264] = bf16( sum_k gw[row][t][k] * emb[row][k*256+e] )
//            (XOR granule swizzle: granule ^= row&7 -> conflict-free reads)
//   phase 2: tower stage-1: acc = aggA @ TW1_t (A straight from LDS)
//   phase 3: th/w2s + stage-2 (verbatim verified tower)
// Eliminates the aggb HBM round-trip (50 MB) and one launch.  embb re-read
// 3x but L3-resident (134 MB, just written).  LDS 75776 B -> 2 blocks/CU.
// ---------------------------------------------------------------------------
__global__ __launch_bounds__(256) void agg_tower(
    const unsigned short* __restrict__ embb,   // [BC][16*256] bf16
    const float* __restrict__ gw,              // [BC][3][16] fp32
    const unsigned short* __restrict__ w1t,    // TW1t [3][128][256] (N-major)
    const float* __restrict__ tb1,
    const unsigned short* __restrict__ w2t,    // TW2t [3][64][128] (N-major)
    const float* __restrict__ tb2,
    float* __restrict__ out)
{
    __shared__ __align__(16) unsigned short sm[37888];   // 75776 B
    // phase 1: aggA @ sm[0..33792) ([128][264]); gws fp32 @ sm[33792..37888)
    // phase 2: Bs @ sm[33792..37888) ([128][32], reuses gws)
    // phase 3: th @ sm[0..17408) ([128][136]); w2s @ sm[17408..26112)
    const int tid = threadIdx.x;
    const int t = blockIdx.y;
    const long b0 = (long)blockIdx.x * 128;
    const int lane16 = tid & 15;
    const int quad = (tid & 63) >> 4;
    const int wave = tid >> 6;
    const int wm = (wave >> 1) * 64;
    const int wn = (wave & 1) * 64;
    const int srow = tid >> 2;
    const int scolsw = (((tid & 3) ^ ((tid >> 3) & 3)) * 8);
    const int cw8 = ((quad ^ ((lane16 >> 1) & 3)) * 8);

    // stage gw panel: gws[128][16] fp32
    float* gws = (float*)(sm + 33792);
    {
        const int r = tid >> 1, j0 = (tid & 1) * 8;
        const float* gp = gw + (b0 + r) * (T_N * K16) + (long)t * K16 + j0;
        *(float4*)&gws[r * 16 + j0]     = *(const float4*)gp;
        *(float4*)&gws[r * 16 + j0 + 4] = *(const float4*)(gp + 4);
    }
    __syncthreads();

    // ---- phase 1: agg into aggA (bf16, granule-swizzled) ----------------
    {
        const int gidx = tid & 31;           // 8-short granule index (0..31)
        const int r0 = tid >> 5;
        const int col8 = gidx * 8;
        #pragma unroll
        for (int i = 0; i < 16; ++i) {
            const int row = r0 + 8 * i;
            const unsigned short* er = embb + (b0 + row) * 4096 + col8;
            float a8[8] = {};
            #pragma unroll
            for (int k = 0; k < 16; ++k) {
                short8 v = *(const short8*)(er + (long)k * 256);
                const float w = gws[row * 16 + k];
                #pragma unroll
                for (int j = 0; j < 8; ++j) a8[j] += w * bf2f((unsigned short)v[j]);
            }
            unsigned rr[4] = {pack2(a8[0], a8[1]), pack2(a8[2], a8[3]),
                              pack2(a8[4], a8[5]), pack2(a8[6], a8[7])};
            *(uint4*)&sm[row * 264 + ((gidx ^ (row & 7)) * 8)] = *(uint4*)rr;
        }
    }
    __syncthreads();

    // ---- phase 2: tower stage-1: acc = aggA @ TW1_t (K=256) -------------
    unsigned short* Bs = sm + 33792;
    const unsigned short* Bb = w1t + (long)t * (TH_N * E_N);
    floatx4 acc[4][4] = {};
    for (int k0 = 0; k0 < 256; k0 += 32) {
#if HAVE_GLL
        load_lds16(Bb + (long)srow * 256 + k0 + scolsw, &Bs[tid * 8]);
        load_lds16(Bb + (long)(srow + 64) * 256 + k0 + scolsw, &Bs[2048 + tid * 8]);
#else
        *(uint4*)&Bs[tid * 8] = *(const uint4*)(Bb + (long)srow * 256 + k0 + scolsw);
        *(uint4*)&Bs[2048 + tid * 8] = *(const uint4*)(Bb + (long)(srow + 64) * 256 + k0 + scolsw);
#endif
        __syncthreads();
        short8 a[4], b[4];
        #pragma unroll
        for (int mi = 0; mi < 4; ++mi) {
            const int row = wm + mi * 16 + lane16;
            const int gg = ((k0 >> 3) + quad) ^ (row & 7);
            a[mi] = *(const short8*)&sm[row * 264 + gg * 8];
        }
        #pragma unroll
        for (int ni = 0; ni < 4; ++ni)
            b[ni] = *(const short8*)&Bs[(wn + ni * 16 + lane16) * 32 + cw8];
        #pragma unroll
        for (int mi = 0; mi < 4; ++mi)
            #pragma unroll
            for (int ni = 0; ni < 4; ++ni)
                acc[mi][ni] = __builtin_amdgcn_mfma_f32_16x16x32_bf16(
                    a[mi], b[ni], acc[mi][ni], 0, 0, 0);
        __syncthreads();
    }

    // ---- phase 3: th epilogue + w2s stage (overlay aggA, now dead) ------
    unsigned short* th  = sm;            // [128][136]
    unsigned short* w2s = sm + 17408;    // [64][136]
    #pragma unroll
    for (int mi = 0; mi < 4; ++mi) {
        #pragma unroll
        for (int ni = 0; ni < 4; ++ni) {
            const int col = wn + ni * 16 + lane16;
            const float bv = tb1[t * TH_N + col];
            #pragma unroll
            for (int r = 0; r < 4; ++r) {
                const int row = wm + mi * 16 + quad * 4 + r;
                th[row * 136 + col] = f2bf(fmaxf(acc[mi][ni][r] + bv, 0.0f));
            }
        }
    }
    #pragma unroll
    for (int i = 0; i < 4; ++i) {
        const int seg = i * 256 + tid;
        const int row = seg >> 4, cb = (seg & 15) * 8;
        *(uint4*)&w2s[row * 136 + cb] =
            *(const uint4*)&w2t[(long)t * (TO_N * TH_N) + (long)row * 128 + cb];
    }
    __syncthreads();

    floatx4 acc2[2][4] = {};
    #pragma unroll
    for (int kk = 0; kk < 4; ++kk) {
        short8 a2[2], b2[4];
        #pragma unroll
        for (int mi = 0; mi < 2; ++mi)
            a2[mi] = *(const short8*)&th[(wave * 32 + mi * 16 + lane16) * 136 + kk * 32 + quad * 8];
        #pragma unroll
        for (int ni = 0; ni < 4; ++ni)
            b2[ni] = *(const short8*)&w2s[(ni * 16 + lane16) * 136 + kk * 32 + quad * 8];
        #pragma unroll
        for (int mi = 0; mi < 2; ++mi)
            #pragma unroll
            for (int ni = 0; ni < 4; ++ni)
                acc2[mi][ni] = __builtin_amdgcn_mfma_f32_16x16x32_bf16(
                    a2[mi], b2[ni], acc2[mi][ni], 0, 0, 0);
    }
    #pragma unroll
    for (int mi = 0; mi < 2; ++mi) {
        #pragma unroll
        for (int ni = 0; ni < 4; ++ni) {
            const int col = ni * 16 + lane16;
            const float bv = tb2[t * TO_N + col];
            #pragma unroll
            for (int r = 0; r < 4; ++r) {
                const int row = wave * 32 + mi * 16 + quad * 4 + r;
                out[(b0 + row) * (T_N * TO_N) + t * TO_N + col] = acc2[mi][ni][r] + bv;
            }
        }
    }
}

// ---------------------------------------------------------------------------
extern "C" void kernel_launch(void* const* d_in, const int* in_sizes, int n_in,
                              void* d_out, int out_size, void* d_ws, size_t ws_size,
                              hipStream_t stream)
{
    const float* x   = (const float*)d_in[0];
    const float* eW1 = (const float*)d_in[1];
    const float* eb1 = (const float*)d_in[2];
    const float* eW2 = (const float*)d_in[3];
    const float* eb2 = (const float*)d_in[4];
    const float* gW1 = (const float*)d_in[5];
    const float* gb1 = (const float*)d_in[6];
    const float* gW2 = (const float*)d_in[7];
    const float* gb2 = (const float*)d_in[8];
    const float* tW1 = (const float*)d_in[9];
    const float* tb1 = (const float*)d_in[10];
    const float* tW2 = (const float*)d_in[11];
    const float* tb2 = (const float*)d_in[12];
    float* out = (float*)d_out;

    char* ws = (char*)d_ws;
    // Persistent weight buffers (bf16, transposed): 13,615,104 B total
    unsigned short* W1t  = (unsigned short*)(ws + 0);          // [16][512][512]
    unsigned short* W2t  = (unsigned short*)(ws + 8388608);    // [16][256][512]
    unsigned short* G1t  = (unsigned short*)(ws + 12582912);   // [3][256][512]
    unsigned short* TW1t = (unsigned short*)(ws + 13369344);   // [3][128][256]
    unsigned short* TW2t = (unsigned short*)(ws + 13565952);   // [3][64][128]
    const size_t WFIX = 13615104;

    // Row-chunk sizing: 18,624 B per row of per-chunk buffers.
    long BCo = 0;
    for (long co = 16384; co >= 128; co >>= 1)
        if (WFIX + (size_t)co * 18624 <= ws_size) { BCo = co; break; }
    if (BCo == 0) return;  // workspace too small — fail cleanly

    char* p = ws + WFIX;
    unsigned short* xb   = (unsigned short*)p; p += BCo * 4096;  // [BCo][G*D]
    unsigned short* ginb = (unsigned short*)p; p += BCo * 3072;  // [BCo][T*D]
    unsigned short* embb = (unsigned short*)p; p += BCo * 8192;  // [BCo][16*E]
    p += BCo * 1536;                                             // (spare)
    float*          gw   = (float*)p;          p += BCo * 192;   // [BCo][T][16]

    const long n_o = B_N / BCo;
    const int panels = (int)(BCo / 128);

    // One launch: all 5 weight transposes (+ input convert when unchunked)
    const long nconv = (n_o == 1) ? BCo : 0;
    prep_kernel<<<dim3((unsigned)(6648 + nconv)), 256, 0, stream>>>(
        eW1, eW2, gW1, tW1, tW2, W1t, W2t, G1t, TW1t, TW2t, x, xb, ginb);

    for (long c = 0; c < n_o; ++c) {
        const float* xc = x + c * BCo * (G_N * D_N);
        float* outc = out + c * BCo * (T_N * TO_N);

        if (n_o > 1)
            convert_inputs<<<BCo, 256, 0, stream>>>(xc, xb, ginb);
        // gate + expert in one launch (gate blocks first, expert after)
        moe_fused<<<dim3((unsigned)(panels * 19)), 256, 0, stream>>>(
            xb, W1t, eb1, W2t, eb2, embb,
            ginb, G1t, gb1, gW2, gb2, gw, panels);
        // agg + towers fused -> out fp32
        agg_tower<<<dim3(panels, 3), 256, 0, stream>>>(
            embb, gw, TW1t, tb1, TW2t, tb2, outc);
    }
}